// Round 10
// baseline (830.987 us; speedup 1.0000x reference)
//
#include <hip/hip_runtime.h>

// Newton-Schulz matrix sqrt, 1024 batches of 128x128 SPD, 5 iterations.
// R14 = R13 (32x32x16 MFMA, correctness-verified) with ks-major fragment
// loading to eliminate R13's source-level register overcommit.
// R13 post-mortem: loading all B-frags (32 regs) + both A-frag sets (32)
// per phase put 144 regs live by construction -> spill (FETCH +57MB,
// WRITE +58MB), 230us. The 32x32 shape itself PASSED (absmax 2^-7) ->
// layouts verified; only the register plan failed.
// R14 phase loop: prefetch ahY only (16) pre-barrier; per ks-round load
// bh0/bl0/bh1/bl1 (16) + per-ks ahZ/alZ (8) -> peak live ~120+misc <=128.
// Per-acc MFMA order unchanged from R13 -> numerics bit-identical.
// Shape motivation (unchanged): 4.85 CU-cy/instr (16x16x32, m06) vs
// 8.07 for 2x FLOPs (32x32x16, m119) -> MFMA pipe 11.2k -> 9.3k cy/iter.
// Kept: R12 stage-ahead dbuf Tq, one barrier/phase; Y/Z swizzle u^=(R&7);
// Tq swizzle u^=((C>>1)&3); split_pair; s_setprio; 8 waves, lb(512,1).

#define NN 128

typedef short bf16x8  __attribute__((ext_vector_type(8)));
typedef short short4v __attribute__((ext_vector_type(4)));
typedef float f32x16  __attribute__((ext_vector_type(16)));

__device__ __forceinline__ float bf2f(short h) {
  union { unsigned u; float f; } c;
  c.u = ((unsigned)(unsigned short)h) << 16;
  return c.f;
}

// D[15:0] = bf16_rne(a), D[31:16] = bf16_rne(b)
__device__ __forceinline__ unsigned cvt_pk_bf16(float a, float b) {
  unsigned r;
  asm("v_cvt_pk_bf16_f32 %0, %1, %2" : "=v"(r) : "v"(a), "v"(b));
  return r;
}

// hp = {trunc16(x1), trunc16(x0)} (1 v_perm_b32);
// lp = {rne16(x1-hi1), rne16(x0-hi0)} (2 and, 2 sub, 1 cvt_pk).
__device__ __forceinline__ void split_pair(float x0, float x1,
                                           unsigned& hp, unsigned& lp) {
  union { float f; unsigned u; } c0, c1; c0.f = x0; c1.f = x1;
  hp = __builtin_amdgcn_perm(c1.u, c0.u, 0x07060302u);
  union { unsigned u; float f; } h0, h1;
  h0.u = c0.u & 0xFFFF0000u;
  h1.u = c1.u & 0xFFFF0000u;
  lp = cvt_pk_bf16(x0 - h0.f, x1 - h1.f);
}

// Swizzled LDS index helpers (index in shorts).
// Y/Z: [R][K], 128x128, unit = K>>3 (16B), unit ^= (R&7).
__device__ __forceinline__ int yix2(int R, int K) {
  return (R << 7) + (((K >> 3) ^ (R & 7)) << 3) + (K & 7);
}
// Tq: [C][K], 128x32, unit = K>>3 (0..3), unit ^= ((C>>1)&3).
__device__ __forceinline__ int tix(int C, int K) {
  return (C << 5) + ((((K >> 3) ^ (C >> 1)) & 3) << 3) + (K & 7);
}

#define YIX(R, K) yix2((R), (K))

#define MFMA3W(ACC, AH, AL, BH, BL)                                        \
  ACC = __builtin_amdgcn_mfma_f32_32x32x16_bf16(AH, BH, ACC, 0, 0, 0);     \
  ACC = __builtin_amdgcn_mfma_f32_32x32x16_bf16(AH, BL, ACC, 0, 0, 0);     \
  ACC = __builtin_amdgcn_mfma_f32_32x32x16_bf16(AL, BH, ACC, 0, 0, 0);

__global__ __launch_bounds__(512, 1)
void ns_sqrt_kernel(const float* __restrict__ A, float* __restrict__ out) {
  __shared__ __align__(16) short Yhi[NN * NN];
  __shared__ __align__(16) short Ylo[NN * NN];
  __shared__ __align__(16) short Zhi[NN * NN];
  __shared__ __align__(16) short Zlo[NN * NN];
  __shared__ __align__(16) short Tq[2][2][NN * 32];  // [buf][hi=0/lo=1]

  // 163,840 B total == exactly the 160 KiB cap; red aliases Tq buf1.
  float* red = reinterpret_cast<float*>(&Tq[1][0][0]);

  const int tid  = threadIdx.x;
  const int wave = tid >> 6;
  const int lane = tid & 63;
  const int l31  = lane & 31;
  const int hig  = lane >> 5;          // 0/1: k-group and +4-row select
  const int hi4  = hig << 2;           // 0 or 4
  const int wr = wave >> 1, wc = wave & 1;
  const int RB = wr << 5, CB = wc << 6;   // 32x64 slab base

  #pragma unroll 1
  for (int sb = 0; sb < 2; ++sb) {
    const int b = (blockIdx.x << 1) + sb;
    const float* Ab = A + (size_t)b * (NN * NN);

    // ---- init: load all of A, Frobenius sum, store unnormalized split A ----
    float ss = 0.f;
    {
      const float4* p = reinterpret_cast<const float4*>(Ab);
      const int row = tid >> 2;          // 0..127
      const int c0  = (tid & 3) << 5;    // 0,32,64,96
      #pragma unroll
      for (int ch = 0; ch < 4; ++ch) {
        float4 v0 = p[row * (NN / 4) + (c0 >> 2) + (ch << 1) + 0];
        float4 v1 = p[row * (NN / 4) + (c0 >> 2) + (ch << 1) + 1];
        ss += v0.x * v0.x + v0.y * v0.y + v0.z * v0.z + v0.w * v0.w;
        ss += v1.x * v1.x + v1.y * v1.y + v1.z * v1.z + v1.w * v1.w;
        uint4 vh, vl;
        split_pair(v0.x, v0.y, vh.x, vl.x);
        split_pair(v0.z, v0.w, vh.y, vl.y);
        split_pair(v1.x, v1.y, vh.z, vl.z);
        split_pair(v1.z, v1.w, vh.w, vl.w);
        const int o = YIX(row, c0 + (ch << 3));
        *(uint4*)&Yhi[o] = vh;
        *(uint4*)&Ylo[o] = vl;
      }
    }
    #pragma unroll
    for (int off = 32; off; off >>= 1) ss += __shfl_xor(ss, off, 64);
    if (lane == 0) red[wave] = ss;
    __syncthreads();
    float tot = 0.f;
    #pragma unroll
    for (int w = 0; w < 8; ++w) tot += red[w];
    const float normA = sqrtf(tot);
    const float rn    = 1.f / normA;
    const float s_out = sqrtf(normA);

    const f32x16 zero16 = {0.f,0.f,0.f,0.f,0.f,0.f,0.f,0.f,
                           0.f,0.f,0.f,0.f,0.f,0.f,0.f,0.f};

    #pragma unroll 1
    for (int it = 1; it <= 5; ++it) {
      const bool doQ = (it >= 2) && (it <= 4);   // it1: Z1 = T; it5: Z unused
      f32x16 accM[2];

      if (it == 1) {
        // M = A slab (symmetric b64 read); normalization folded via mscale
        #pragma unroll
        for (int j = 0; j < 2; ++j) {
          #pragma unroll
          for (int g = 0; g < 4; ++g) {
            const int col  = CB + (j << 5) + l31;
            const int row0 = RB + (g << 3) + hi4;
            const int o = YIX(col, row0);
            short4v h = *(const short4v*)&Yhi[o];
            short4v l = *(const short4v*)&Ylo[o];
            #pragma unroll
            for (int r = 0; r < 4; ++r)
              accM[j][(g << 2) + r] = bf2f(h[r]) + bf2f(l[r]);
          }
        }
      } else {
        // M = Z*Y  (A = Z rows; B = Y rows via symmetry), ks-major.
        accM[0] = zero16; accM[1] = zero16;
        #pragma unroll
        for (int ks = 0; ks < 8; ++ks) {
          const int k0 = (ks << 4) + (hig << 3);
          const int oa = YIX(RB + l31, k0);
          bf16x8 ah = *(const bf16x8*)&Zhi[oa];
          bf16x8 al = *(const bf16x8*)&Zlo[oa];
          bf16x8 bh[2], bl[2];
          #pragma unroll
          for (int j = 0; j < 2; ++j) {
            const int o = YIX(CB + (j << 5) + l31, k0);
            bh[j] = *(const bf16x8*)&Yhi[o];
            bl[j] = *(const bf16x8*)&Ylo[o];
          }
          #pragma unroll
          for (int j = 0; j < 2; ++j) { MFMA3W(accM[j], ah, al, bh[j], bl[j]); }
        }
      }

      // T = 1.5 I - 0.5*mscale*M, split immediately into packed regs
      const float mscale = (it == 1) ? rn : 1.0f;
      unsigned tp[2][4][2], tl[2][4][2];
      #pragma unroll
      for (int j = 0; j < 2; ++j) {
        #pragma unroll
        for (int g = 0; g < 4; ++g) {
          float tv[4];
          #pragma unroll
          for (int r = 0; r < 4; ++r) {
            float t0 = -0.5f * mscale * accM[j][(g << 2) + r];
            if (RB + (g << 3) + hi4 + r == CB + (j << 5) + l31) t0 += 1.5f;
            tv[r] = t0;
          }
          split_pair(tv[0], tv[1], tp[j][g][0], tl[j][g][0]);
          split_pair(tv[2], tv[3], tp[j][g][1], tl[j][g][1]);
        }
      }

      f32x16 accP[2], accQ[2];
      accP[0] = zero16; accP[1] = zero16;
      accQ[0] = zero16; accQ[1] = zero16;

      // Prologue: stage phase-0 panel into buf0 (buf0's last readers were
      // prev iter's phase 2, drained 2 barriers ago).
      if (wr == 0) {
        #pragma unroll
        for (int j = 0; j < 2; ++j) {
          #pragma unroll
          for (int g = 0; g < 4; ++g) {
            const int colq = CB + (j << 5) + l31;
            const int kp0  = (g << 3) + hi4;
            const int oq   = tix(colq, kp0);
            *(uint2*)&Tq[0][0][oq] = make_uint2(tp[j][g][0], tp[j][g][1]);
            *(uint2*)&Tq[0][1][oq] = make_uint2(tl[j][g][0], tl[j][g][1]);
          }
        }
      }

      // 4 phases, double-buffered panels, stage-ahead schedule (R12),
      // ks-major fragment loads (<=128 live regs by construction).
      #pragma unroll 1
      for (int t = 0; t < 4; ++t) {
        const short* th = &Tq[t & 1][0][0];
        const short* tg = &Tq[t & 1][1][0];
        short* sh = &Tq[(t + 1) & 1][0][0];
        short* sg = &Tq[(t + 1) & 1][1][0];

        const int kb = t << 5;
        // Pre-barrier: Y A-frags only (16 regs across the barrier).
        bf16x8 ahY[2], alY[2];
        #pragma unroll
        for (int ks = 0; ks < 2; ++ks) {
          const int o = YIX(RB + l31, kb + (ks << 4) + (hig << 3));
          ahY[ks] = *(const bf16x8*)&Yhi[o];
          alY[ks] = *(const bf16x8*)&Ylo[o];
        }

        __syncthreads();                   // publish Tq[t&1]

        // Stage NEXT phase's panel under the MFMA shadow.
        if (t < 3 && wr == t + 1) {
          #pragma unroll
          for (int j = 0; j < 2; ++j) {
            #pragma unroll
            for (int g = 0; g < 4; ++g) {
              const int colq = CB + (j << 5) + l31;
              const int kp0  = (g << 3) + hi4;
              const int oq   = tix(colq, kp0);
              *(uint2*)&sh[oq] = make_uint2(tp[j][g][0], tp[j][g][1]);
              *(uint2*)&sg[oq] = make_uint2(tl[j][g][0], tl[j][g][1]);
            }
          }
        }

        __builtin_amdgcn_s_setprio(1);
        #pragma unroll
        for (int ks = 0; ks < 2; ++ks) {
          const int kq = (ks << 4) + (hig << 3);
          bf16x8 bh0, bl0, bh1, bl1;
          {
            const int o = tix(CB + l31, kq);
            bh0 = *(const bf16x8*)&th[o];
            bl0 = *(const bf16x8*)&tg[o];
          }
          {
            const int o = tix(CB + 32 + l31, kq);
            bh1 = *(const bf16x8*)&th[o];
            bl1 = *(const bf16x8*)&tg[o];
          }
          if (doQ) {
            const int oz = YIX(RB + l31, kb + kq);
            bf16x8 ahZ = *(const bf16x8*)&Zhi[oz];
            bf16x8 alZ = *(const bf16x8*)&Zlo[oz];
            MFMA3W(accP[0], ahY[ks], alY[ks], bh0, bl0);
            MFMA3W(accP[1], ahY[ks], alY[ks], bh1, bl1);
            MFMA3W(accQ[0], ahZ, alZ, bh0, bl0);
            MFMA3W(accQ[1], ahZ, alZ, bh1, bl1);
          } else {
            MFMA3W(accP[0], ahY[ks], alY[ks], bh0, bl0);
            MFMA3W(accP[1], ahY[ks], alY[ks], bh1, bl1);
          }
        }
        __builtin_amdgcn_s_setprio(0);
      }
      __syncthreads();   // all reads of Y/Z/Tq complete

      if (it < 5) {
        // write-back (packed b64 "transposed" store = same matrix by symmetry)
        const float yscale = (it == 1) ? rn : 1.0f;
        #pragma unroll
        for (int j = 0; j < 2; ++j) {
          #pragma unroll
          for (int g = 0; g < 4; ++g) {
            const int col  = CB + (j << 5) + l31;
            const int row0 = RB + (g << 3) + hi4;
            const int o = YIX(col, row0);
            unsigned h01, l01, h23, l23;
            split_pair(yscale * accP[j][(g << 2) + 0],
                       yscale * accP[j][(g << 2) + 1], h01, l01);
            split_pair(yscale * accP[j][(g << 2) + 2],
                       yscale * accP[j][(g << 2) + 3], h23, l23);
            *(uint2*)&Yhi[o] = make_uint2(h01, h23);
            *(uint2*)&Ylo[o] = make_uint2(l01, l23);
            if (it == 1) {
              // Z1 = T: reuse the packed split regs directly
              *(uint2*)&Zhi[o] = make_uint2(tp[j][g][0], tp[j][g][1]);
              *(uint2*)&Zlo[o] = make_uint2(tl[j][g][0], tl[j][g][1]);
            } else {
              split_pair(accQ[j][(g << 2) + 0], accQ[j][(g << 2) + 1], h01, l01);
              split_pair(accQ[j][(g << 2) + 2], accQ[j][(g << 2) + 3], h23, l23);
              *(uint2*)&Zhi[o] = make_uint2(h01, h23);
              *(uint2*)&Zlo[o] = make_uint2(l01, l23);
            }
          }
        }
        __syncthreads();
      } else {
        // final: out = Y5 * sqrt(normA)  (fire-and-forget; overlaps next init)
        float* ob = out + (size_t)b * (NN * NN);
        #pragma unroll
        for (int j = 0; j < 2; ++j) {
          #pragma unroll
          for (int g = 0; g < 4; ++g) {
            const int col  = CB + (j << 5) + l31;
            const int row0 = RB + (g << 3) + hi4;
            #pragma unroll
            for (int r = 0; r < 4; ++r)
              ob[(size_t)(row0 + r) * NN + col] = accP[j][(g << 2) + r] * s_out;
          }
        }
      }
    }
  }
}

extern "C" void kernel_launch(void* const* d_in, const int* in_sizes, int n_in,
                              void* d_out, int out_size, void* d_ws, size_t ws_size,
                              hipStream_t stream) {
  const float* A = (const float*)d_in[0];
  float* out = (float*)d_out;
  ns_sqrt_kernel<<<dim3(512), dim3(512), 0, stream>>>(A, out);
}

// Round 11
// 260.924 us; speedup vs baseline: 3.1848x; 3.1848x over previous
//
#include <hip/hip_runtime.h>

// Newton-Schulz matrix sqrt, 1024 batches of 128x128 SPD, 5 iterations.
// R15 = R12 (verified 172.5us) + next-batch A prefetch at it5 [only change].
// R13/R14 post-mortem: 32x32x16 needs f32x16 accs = 16-reg-aligned tuples;
// 4 tuples + frags cannot tile into the 128-VGPR budget -> compiler demotes
// vectors to scratch (R14: FETCH 591MB WRITE 741MB, 765us). Shape dead at
// this occupancy; f32x4 granularity of 16x16x32 is what fits. Reverted.
// R15 tweak: at it5 accQ/accM are dead (-64 regs), so prefetching the next
// batch's 8 x float4 into regs right after the it5 post-loop barrier is
// pressure-neutral; hides ~1-2k cy of HBM/L3 latency under the out-store
// and loop tail. Same values, same order -> absmax bit-identical.
// R12 structure kept verbatim:
//   - 8 waves (4x2), 512 thr, lb(512,1), 2 batches/block, grid 512
//   - Tq double-buffered, ONE barrier/phase, stage-ahead under MFMA shadow
//   - Y/Z swizzle unit^=(R&7); Tq swizzle unit^=((C>>1)&3) (R11 fix)
//   - red[] aliases Tq buf1; split_pair; s_setprio around MFMA cluster.

#define NN 128

typedef short bf16x8  __attribute__((ext_vector_type(8)));
typedef short short4v __attribute__((ext_vector_type(4)));
typedef float f32x4   __attribute__((ext_vector_type(4)));

__device__ __forceinline__ float bf2f(short h) {
  union { unsigned u; float f; } c;
  c.u = ((unsigned)(unsigned short)h) << 16;
  return c.f;
}

// D[15:0] = bf16_rne(a), D[31:16] = bf16_rne(b)
__device__ __forceinline__ unsigned cvt_pk_bf16(float a, float b) {
  unsigned r;
  asm("v_cvt_pk_bf16_f32 %0, %1, %2" : "=v"(r) : "v"(a), "v"(b));
  return r;
}

// hp = {trunc16(x1), trunc16(x0)} (1 v_perm_b32);
// lp = {rne16(x1-hi1), rne16(x0-hi0)} (2 and, 2 sub, 1 cvt_pk).
__device__ __forceinline__ void split_pair(float x0, float x1,
                                           unsigned& hp, unsigned& lp) {
  union { float f; unsigned u; } c0, c1; c0.f = x0; c1.f = x1;
  hp = __builtin_amdgcn_perm(c1.u, c0.u, 0x07060302u);
  union { unsigned u; float f; } h0, h1;
  h0.u = c0.u & 0xFFFF0000u;
  h1.u = c1.u & 0xFFFF0000u;
  lp = cvt_pk_bf16(x0 - h0.f, x1 - h1.f);
}

// Swizzled LDS index helpers (index in shorts).
// Y/Z: [R][K], 128x128, unit = K>>3 (16B), unit ^= (R&7).
__device__ __forceinline__ int yix2(int R, int K) {
  return (R << 7) + (((K >> 3) ^ (R & 7)) << 3) + (K & 7);
}
// Tq: [C][K], 128x32, unit = K>>3 (0..3), unit ^= ((C>>1)&3).
__device__ __forceinline__ int tix(int C, int K) {
  return (C << 5) + ((((K >> 3) ^ (C >> 1)) & 3) << 3) + (K & 7);
}

#define YIX(R, K) yix2((R), (K))

#define MFMA3(ACC, AH, AL, BH, BL)                                        \
  ACC = __builtin_amdgcn_mfma_f32_16x16x32_bf16(AH, BH, ACC, 0, 0, 0);    \
  ACC = __builtin_amdgcn_mfma_f32_16x16x32_bf16(AH, BL, ACC, 0, 0, 0);    \
  ACC = __builtin_amdgcn_mfma_f32_16x16x32_bf16(AL, BH, ACC, 0, 0, 0);

__global__ __launch_bounds__(512, 1)
void ns_sqrt_kernel(const float* __restrict__ A, float* __restrict__ out) {
  __shared__ __align__(16) short Yhi[NN * NN];
  __shared__ __align__(16) short Ylo[NN * NN];
  __shared__ __align__(16) short Zhi[NN * NN];
  __shared__ __align__(16) short Zlo[NN * NN];
  __shared__ __align__(16) short Tq[2][2][NN * 32];  // [buf][hi=0/lo=1]

  // 163,840 B total == exactly the 160 KiB cap; red aliases Tq buf1.
  float* red = reinterpret_cast<float*>(&Tq[1][0][0]);

  const int tid  = threadIdx.x;
  const int wave = tid >> 6;
  const int lane = tid & 63;
  const int quad = lane >> 4;
  const int lrow = lane & 15;
  const int wr = wave >> 1, wc = wave & 1;
  const int RB = wr << 5, CB = wc << 6;   // 32x64 slab base

  // Next-batch A prefetch registers (live only init<->it5 tail; static idx).
  float4 pf[8];
  {
    const float* Ab0 = A + (size_t)(blockIdx.x << 1) * (NN * NN);
    const float4* p0 = reinterpret_cast<const float4*>(Ab0);
    const int row = tid >> 2;            // 0..127
    const int c0q = (tid & 3) << 3;      // float4-index base: 0,8,16,24
    #pragma unroll
    for (int q = 0; q < 8; ++q) pf[q] = p0[row * (NN / 4) + c0q + q];
  }

  #pragma unroll 1
  for (int sb = 0; sb < 2; ++sb) {
    const int b = (blockIdx.x << 1) + sb;

    // ---- init: consume prefetched A, Frobenius sum, store split A ----
    float ss = 0.f;
    {
      const int row = tid >> 2;          // 0..127
      const int c0  = (tid & 3) << 5;    // 0,32,64,96
      #pragma unroll
      for (int ch = 0; ch < 4; ++ch) {
        float4 v0 = pf[(ch << 1) + 0];
        float4 v1 = pf[(ch << 1) + 1];
        ss += v0.x * v0.x + v0.y * v0.y + v0.z * v0.z + v0.w * v0.w;
        ss += v1.x * v1.x + v1.y * v1.y + v1.z * v1.z + v1.w * v1.w;
        uint4 vh, vl;
        split_pair(v0.x, v0.y, vh.x, vl.x);
        split_pair(v0.z, v0.w, vh.y, vl.y);
        split_pair(v1.x, v1.y, vh.z, vl.z);
        split_pair(v1.z, v1.w, vh.w, vl.w);
        const int o = YIX(row, c0 + (ch << 3));
        *(uint4*)&Yhi[o] = vh;
        *(uint4*)&Ylo[o] = vl;
      }
    }
    #pragma unroll
    for (int off = 32; off; off >>= 1) ss += __shfl_xor(ss, off, 64);
    if (lane == 0) red[wave] = ss;
    __syncthreads();
    float tot = 0.f;
    #pragma unroll
    for (int w = 0; w < 8; ++w) tot += red[w];
    const float normA = sqrtf(tot);
    const float rn    = 1.f / normA;
    const float s_out = sqrtf(normA);

    const f32x4 zero4 = {0.f, 0.f, 0.f, 0.f};

    #pragma unroll 1
    for (int it = 1; it <= 5; ++it) {
      const bool doQ = (it >= 2) && (it <= 4);   // it1: Z1 = T; it5: Z unused
      f32x4 accM[2][4];
      f32x4 accP[2][4];
      f32x4 accQ[2][4];
      #pragma unroll
      for (int i = 0; i < 2; ++i)
        #pragma unroll
        for (int j = 0; j < 4; ++j) { accP[i][j] = zero4; accQ[i][j] = zero4; }

      if (it == 1) {
        // M = A slab (symmetric b64 read); normalization folded via mscale
        #pragma unroll
        for (int i = 0; i < 2; ++i)
          #pragma unroll
          for (int j = 0; j < 4; ++j) {
            const int col  = CB + 16*j + lrow;
            const int row0 = RB + 16*i + (quad << 2);
            const int o = YIX(col, row0);
            short4v h = *(const short4v*)&Yhi[o];
            short4v l = *(const short4v*)&Ylo[o];
            #pragma unroll
            for (int r = 0; r < 4; ++r) accM[i][j][r] = bf2f(h[r]) + bf2f(l[r]);
          }
      } else {
        // M = Z*Y  (A = Z rows; B = Y rows via symmetry)
        #pragma unroll
        for (int i = 0; i < 2; ++i)
          #pragma unroll
          for (int j = 0; j < 4; ++j) accM[i][j] = zero4;
        #pragma unroll
        for (int kc = 0; kc < 4; ++kc) {
          const int k0 = (kc << 5) + (quad << 3);
          bf16x8 ah[2], al[2], bh[4], bl[4];
          #pragma unroll
          for (int i = 0; i < 2; ++i) {
            const int o = YIX(RB + lrow + 16*i, k0);
            ah[i] = *(const bf16x8*)&Zhi[o];
            al[i] = *(const bf16x8*)&Zlo[o];
          }
          #pragma unroll
          for (int j = 0; j < 4; ++j) {
            const int o = YIX(CB + lrow + 16*j, k0);
            bh[j] = *(const bf16x8*)&Yhi[o];
            bl[j] = *(const bf16x8*)&Ylo[o];
          }
          #pragma unroll
          for (int i = 0; i < 2; ++i)
            #pragma unroll
            for (int j = 0; j < 4; ++j) { MFMA3(accM[i][j], ah[i], al[i], bh[j], bl[j]); }
        }
      }

      // T = 1.5 I - 0.5*mscale*M, split immediately into packed regs
      const float mscale = (it == 1) ? rn : 1.0f;
      unsigned tp[2][4][2], tl[2][4][2];
      #pragma unroll
      for (int i = 0; i < 2; ++i)
        #pragma unroll
        for (int j = 0; j < 4; ++j) {
          float tv[4];
          #pragma unroll
          for (int r = 0; r < 4; ++r) {
            float t0 = -0.5f * mscale * accM[i][j][r];
            if (RB + 16*i + (quad << 2) + r == CB + 16*j + lrow) t0 += 1.5f;
            tv[r] = t0;
          }
          split_pair(tv[0], tv[1], tp[i][j][0], tl[i][j][0]);
          split_pair(tv[2], tv[3], tp[i][j][1], tl[i][j][1]);
        }

      // Prologue: stage phase-0 panel into buf0 (buf0's last readers were
      // prev iter's phase 2, drained 2 barriers ago).
      if (wr == 0) {
        #pragma unroll
        for (int i = 0; i < 2; ++i) {
          const int kp0 = (i << 4) + (quad << 2);
          #pragma unroll
          for (int j = 0; j < 4; ++j) {
            const int col = CB + 16*j + lrow;
            const int o = tix(col, kp0);
            *(uint2*)&Tq[0][0][o] = make_uint2(tp[i][j][0], tp[i][j][1]);
            *(uint2*)&Tq[0][1][o] = make_uint2(tl[i][j][0], tl[i][j][1]);
          }
        }
      }

      // 4 phases, double-buffered panels, STAGE-AHEAD schedule:
      // phase t: [prefetch A-frags] barrier [B-frags from buf t] +
      //          [stage buf t+1 under MFMA shadow] + [MFMA].
      #pragma unroll 1
      for (int t = 0; t < 4; ++t) {
        const short* th = &Tq[t & 1][0][0];
        const short* tg = &Tq[t & 1][1][0];
        short* sh = &Tq[(t + 1) & 1][0][0];
        short* sg = &Tq[(t + 1) & 1][1][0];

        // A-fragments depend only on Y/Z (stable all phase-loop long):
        // issued above the barrier so their latency hides under the wait.
        const int k0 = (t << 5) + (quad << 3);
        bf16x8 ahY[2], alY[2], ahZ[2], alZ[2];
        #pragma unroll
        for (int i = 0; i < 2; ++i) {
          const int o = YIX(RB + lrow + 16*i, k0);
          ahY[i] = *(const bf16x8*)&Yhi[o];
          alY[i] = *(const bf16x8*)&Ylo[o];
        }
        if (doQ) {
          #pragma unroll
          for (int i = 0; i < 2; ++i) {
            const int o = YIX(RB + lrow + 16*i, k0);
            ahZ[i] = *(const bf16x8*)&Zhi[o];
            alZ[i] = *(const bf16x8*)&Zlo[o];
          }
        }

        __syncthreads();                   // publish Tq[t&1]

        const int kq = quad << 3;
        bf16x8 bh[4], bl[4];
        #pragma unroll
        for (int j = 0; j < 4; ++j) {
          const int o = tix(CB + 16*j + lrow, kq);
          bh[j] = *(const bf16x8*)&th[o];
          bl[j] = *(const bf16x8*)&tg[o];
        }

        // Stage NEXT phase's panel into the free buffer, hidden under the
        // MFMA cluster (buf[(t+1)&1] readers drained at this barrier).
        if (t < 3 && wr == t + 1) {
          #pragma unroll
          for (int i = 0; i < 2; ++i) {
            const int kp0 = (i << 4) + (quad << 2);
            #pragma unroll
            for (int j = 0; j < 4; ++j) {
              const int col = CB + 16*j + lrow;
              const int o = tix(col, kp0);
              *(uint2*)&sh[o] = make_uint2(tp[i][j][0], tp[i][j][1]);
              *(uint2*)&sg[o] = make_uint2(tl[i][j][0], tl[i][j][1]);
            }
          }
        }

        __builtin_amdgcn_s_setprio(1);
        #pragma unroll
        for (int i = 0; i < 2; ++i)
          #pragma unroll
          for (int j = 0; j < 4; ++j) { MFMA3(accP[i][j], ahY[i], alY[i], bh[j], bl[j]); }
        if (doQ) {
          #pragma unroll
          for (int i = 0; i < 2; ++i)
            #pragma unroll
            for (int j = 0; j < 4; ++j) { MFMA3(accQ[i][j], ahZ[i], alZ[i], bh[j], bl[j]); }
        }
        __builtin_amdgcn_s_setprio(0);
      }
      __syncthreads();   // all reads of Y/Z/Tq complete

      if (it < 5) {
        // write-back (packed b64 "transposed" store = same matrix by symmetry)
        const float yscale = (it == 1) ? rn : 1.0f;
        #pragma unroll
        for (int i = 0; i < 2; ++i)
          #pragma unroll
          for (int j = 0; j < 4; ++j) {
            const int col  = CB + 16*j + lrow;
            const int row0 = RB + 16*i + (quad << 2);
            const int o = YIX(col, row0);
            unsigned h01, l01, h23, l23;
            split_pair(yscale * accP[i][j][0], yscale * accP[i][j][1], h01, l01);
            split_pair(yscale * accP[i][j][2], yscale * accP[i][j][3], h23, l23);
            *(uint2*)&Yhi[o] = make_uint2(h01, h23);
            *(uint2*)&Ylo[o] = make_uint2(l01, l23);
            if (it == 1) {
              // Z1 = T: reuse the packed split regs directly
              *(uint2*)&Zhi[o] = make_uint2(tp[i][j][0], tp[i][j][1]);
              *(uint2*)&Zlo[o] = make_uint2(tl[i][j][0], tl[i][j][1]);
            } else {
              split_pair(accQ[i][j][0], accQ[i][j][1], h01, l01);
              split_pair(accQ[i][j][2], accQ[i][j][3], h23, l23);
              *(uint2*)&Zhi[o] = make_uint2(h01, h23);
              *(uint2*)&Zlo[o] = make_uint2(l01, l23);
            }
          }
        __syncthreads();
      } else {
        // Prefetch next batch's A while the out-store drains (accQ/accM
        // dead here -> pressure-neutral; hides HBM/L3 latency under the
        // store tail + loop-back init).
        if (sb == 0) {
          const float* An = A + (size_t)(b + 1) * (NN * NN);
          const float4* pn = reinterpret_cast<const float4*>(An);
          const int row = tid >> 2;
          const int c0q = (tid & 3) << 3;
          #pragma unroll
          for (int q = 0; q < 8; ++q) pf[q] = pn[row * (NN / 4) + c0q + q];
        }
        // final: out = Y5 * sqrt(normA)  (fire-and-forget; overlaps next init)
        float* ob = out + (size_t)b * (NN * NN);
        #pragma unroll
        for (int i = 0; i < 2; ++i)
          #pragma unroll
          for (int j = 0; j < 4; ++j) {
            const int col  = CB + 16*j + lrow;
            const int row0 = RB + 16*i + (quad << 2);
            #pragma unroll
            for (int r = 0; r < 4; ++r)
              ob[(size_t)(row0 + r) * NN + col] = accP[i][j][r] * s_out;
          }
      }
    }
  }
}

extern "C" void kernel_launch(void* const* d_in, const int* in_sizes, int n_in,
                              void* d_out, int out_size, void* d_ws, size_t ws_size,
                              hipStream_t stream) {
  const float* A = (const float*)d_in[0];
  float* out = (float*)d_out;
  ns_sqrt_kernel<<<dim3(512), dim3(512), 0, stream>>>(A, out);
}

// Round 12
// 232.547 us; speedup vs baseline: 3.5734x; 1.1220x over previous
//
#include <hip/hip_runtime.h>

// Newton-Schulz matrix sqrt, 1024 batches of 128x128 SPD, 5 iterations.
// R16 = R12 verbatim (session-best: 172.5us rocprof / 233us harness).
// R15 post-mortem: the next-batch register prefetch wrote pf[8] INSIDE the
// it-loop (under it==5), so the 32 regs were live across the whole it-loop
// (compiler can't prove last-iteration-only) -> spill (FETCH +22MB, WRITE
// +25MB, 199us). Liveness ledger across R6/R8/R13/R14/R15: R12's register
// plan is exactly at the 128-VGPR capacity; ANY added cross-loop live state
// spills. Only pressure-neutral changes (R7 split_pair, R11 swizzle fix,
// R12 stage-ahead) ever held or won.
// Structure (verified):
//   - 8 waves (4x2 grid), 512 thr, lb(512,1), 2 batches/block, grid 512
//   - Tq double-buffered, ONE barrier/phase, stage-ahead under MFMA shadow
//   - Y/Z swizzle unit^=(R&7); Tq swizzle unit^=((C>>1)&3) (R11, per-8-lane
//     -pass bank model; conflicts 1.835e7 = b128 width-aliasing floor)
//   - red[] aliases Tq buf1; split_pair (perm+cvt_pk); s_setprio on MFMA.
// At 36% of the 2495 TF MFMA ceiling -- the known limit of barrier-synced
// 2-phase 128-tile schedules; NS's serial dependency (T needs all of M,
// next iter needs full writeback) blocks deeper pipelining at this
// LDS/VGPR budget. Remaining candidate: it5-epilogue init fusion via LDS.

#define NN 128

typedef short bf16x8  __attribute__((ext_vector_type(8)));
typedef short short4v __attribute__((ext_vector_type(4)));
typedef float f32x4   __attribute__((ext_vector_type(4)));

__device__ __forceinline__ float bf2f(short h) {
  union { unsigned u; float f; } c;
  c.u = ((unsigned)(unsigned short)h) << 16;
  return c.f;
}

// D[15:0] = bf16_rne(a), D[31:16] = bf16_rne(b)
__device__ __forceinline__ unsigned cvt_pk_bf16(float a, float b) {
  unsigned r;
  asm("v_cvt_pk_bf16_f32 %0, %1, %2" : "=v"(r) : "v"(a), "v"(b));
  return r;
}

// hp = {trunc16(x1), trunc16(x0)} (1 v_perm_b32);
// lp = {rne16(x1-hi1), rne16(x0-hi0)} (2 and, 2 sub, 1 cvt_pk).
__device__ __forceinline__ void split_pair(float x0, float x1,
                                           unsigned& hp, unsigned& lp) {
  union { float f; unsigned u; } c0, c1; c0.f = x0; c1.f = x1;
  hp = __builtin_amdgcn_perm(c1.u, c0.u, 0x07060302u);
  union { unsigned u; float f; } h0, h1;
  h0.u = c0.u & 0xFFFF0000u;
  h1.u = c1.u & 0xFFFF0000u;
  lp = cvt_pk_bf16(x0 - h0.f, x1 - h1.f);
}

// Swizzled LDS index helpers (index in shorts).
// Y/Z: [R][K], 128x128, unit = K>>3 (16B), unit ^= (R&7).
__device__ __forceinline__ int yix2(int R, int K) {
  return (R << 7) + (((K >> 3) ^ (R & 7)) << 3) + (K & 7);
}
// Tq: [C][K], 128x32, unit = K>>3 (0..3), unit ^= ((C>>1)&3).
__device__ __forceinline__ int tix(int C, int K) {
  return (C << 5) + ((((K >> 3) ^ (C >> 1)) & 3) << 3) + (K & 7);
}

#define YIX(R, K) yix2((R), (K))

#define MFMA3(ACC, AH, AL, BH, BL)                                        \
  ACC = __builtin_amdgcn_mfma_f32_16x16x32_bf16(AH, BH, ACC, 0, 0, 0);    \
  ACC = __builtin_amdgcn_mfma_f32_16x16x32_bf16(AH, BL, ACC, 0, 0, 0);    \
  ACC = __builtin_amdgcn_mfma_f32_16x16x32_bf16(AL, BH, ACC, 0, 0, 0);

__global__ __launch_bounds__(512, 1)
void ns_sqrt_kernel(const float* __restrict__ A, float* __restrict__ out) {
  __shared__ __align__(16) short Yhi[NN * NN];
  __shared__ __align__(16) short Ylo[NN * NN];
  __shared__ __align__(16) short Zhi[NN * NN];
  __shared__ __align__(16) short Zlo[NN * NN];
  __shared__ __align__(16) short Tq[2][2][NN * 32];  // [buf][hi=0/lo=1]

  // 163,840 B total == exactly the 160 KiB cap; red aliases Tq buf1.
  float* red = reinterpret_cast<float*>(&Tq[1][0][0]);

  const int tid  = threadIdx.x;
  const int wave = tid >> 6;
  const int lane = tid & 63;
  const int quad = lane >> 4;
  const int lrow = lane & 15;
  const int wr = wave >> 1, wc = wave & 1;
  const int RB = wr << 5, CB = wc << 6;   // 32x64 slab base

  #pragma unroll 1
  for (int sb = 0; sb < 2; ++sb) {
    const int b = (blockIdx.x << 1) + sb;
    const float* Ab = A + (size_t)b * (NN * NN);

    // ---- init: load all of A, Frobenius sum, store unnormalized split A ----
    float ss = 0.f;
    {
      const float4* p = reinterpret_cast<const float4*>(Ab);
      const int row = tid >> 2;          // 0..127
      const int c0  = (tid & 3) << 5;    // 0,32,64,96
      #pragma unroll
      for (int ch = 0; ch < 4; ++ch) {
        float4 v0 = p[row * (NN / 4) + (c0 >> 2) + (ch << 1) + 0];
        float4 v1 = p[row * (NN / 4) + (c0 >> 2) + (ch << 1) + 1];
        ss += v0.x * v0.x + v0.y * v0.y + v0.z * v0.z + v0.w * v0.w;
        ss += v1.x * v1.x + v1.y * v1.y + v1.z * v1.z + v1.w * v1.w;
        uint4 vh, vl;
        split_pair(v0.x, v0.y, vh.x, vl.x);
        split_pair(v0.z, v0.w, vh.y, vl.y);
        split_pair(v1.x, v1.y, vh.z, vl.z);
        split_pair(v1.z, v1.w, vh.w, vl.w);
        const int o = YIX(row, c0 + (ch << 3));
        *(uint4*)&Yhi[o] = vh;
        *(uint4*)&Ylo[o] = vl;
      }
    }
    #pragma unroll
    for (int off = 32; off; off >>= 1) ss += __shfl_xor(ss, off, 64);
    if (lane == 0) red[wave] = ss;
    __syncthreads();
    float tot = 0.f;
    #pragma unroll
    for (int w = 0; w < 8; ++w) tot += red[w];
    const float normA = sqrtf(tot);
    const float rn    = 1.f / normA;
    const float s_out = sqrtf(normA);

    const f32x4 zero4 = {0.f, 0.f, 0.f, 0.f};

    #pragma unroll 1
    for (int it = 1; it <= 5; ++it) {
      const bool doQ = (it >= 2) && (it <= 4);   // it1: Z1 = T; it5: Z unused
      f32x4 accM[2][4];
      f32x4 accP[2][4];
      f32x4 accQ[2][4];
      #pragma unroll
      for (int i = 0; i < 2; ++i)
        #pragma unroll
        for (int j = 0; j < 4; ++j) { accP[i][j] = zero4; accQ[i][j] = zero4; }

      if (it == 1) {
        // M = A slab (symmetric b64 read); normalization folded via mscale
        #pragma unroll
        for (int i = 0; i < 2; ++i)
          #pragma unroll
          for (int j = 0; j < 4; ++j) {
            const int col  = CB + 16*j + lrow;
            const int row0 = RB + 16*i + (quad << 2);
            const int o = YIX(col, row0);
            short4v h = *(const short4v*)&Yhi[o];
            short4v l = *(const short4v*)&Ylo[o];
            #pragma unroll
            for (int r = 0; r < 4; ++r) accM[i][j][r] = bf2f(h[r]) + bf2f(l[r]);
          }
      } else {
        // M = Z*Y  (A = Z rows; B = Y rows via symmetry)
        #pragma unroll
        for (int i = 0; i < 2; ++i)
          #pragma unroll
          for (int j = 0; j < 4; ++j) accM[i][j] = zero4;
        #pragma unroll
        for (int kc = 0; kc < 4; ++kc) {
          const int k0 = (kc << 5) + (quad << 3);
          bf16x8 ah[2], al[2], bh[4], bl[4];
          #pragma unroll
          for (int i = 0; i < 2; ++i) {
            const int o = YIX(RB + lrow + 16*i, k0);
            ah[i] = *(const bf16x8*)&Zhi[o];
            al[i] = *(const bf16x8*)&Zlo[o];
          }
          #pragma unroll
          for (int j = 0; j < 4; ++j) {
            const int o = YIX(CB + lrow + 16*j, k0);
            bh[j] = *(const bf16x8*)&Yhi[o];
            bl[j] = *(const bf16x8*)&Ylo[o];
          }
          #pragma unroll
          for (int i = 0; i < 2; ++i)
            #pragma unroll
            for (int j = 0; j < 4; ++j) { MFMA3(accM[i][j], ah[i], al[i], bh[j], bl[j]); }
        }
      }

      // T = 1.5 I - 0.5*mscale*M, split immediately into packed regs
      const float mscale = (it == 1) ? rn : 1.0f;
      unsigned tp[2][4][2], tl[2][4][2];
      #pragma unroll
      for (int i = 0; i < 2; ++i)
        #pragma unroll
        for (int j = 0; j < 4; ++j) {
          float tv[4];
          #pragma unroll
          for (int r = 0; r < 4; ++r) {
            float t0 = -0.5f * mscale * accM[i][j][r];
            if (RB + 16*i + (quad << 2) + r == CB + 16*j + lrow) t0 += 1.5f;
            tv[r] = t0;
          }
          split_pair(tv[0], tv[1], tp[i][j][0], tl[i][j][0]);
          split_pair(tv[2], tv[3], tp[i][j][1], tl[i][j][1]);
        }

      // Prologue: stage phase-0 panel into buf0 (buf0's last readers were
      // prev iter's phase 2, drained 2 barriers ago).
      if (wr == 0) {
        #pragma unroll
        for (int i = 0; i < 2; ++i) {
          const int kp0 = (i << 4) + (quad << 2);
          #pragma unroll
          for (int j = 0; j < 4; ++j) {
            const int col = CB + 16*j + lrow;
            const int o = tix(col, kp0);
            *(uint2*)&Tq[0][0][o] = make_uint2(tp[i][j][0], tp[i][j][1]);
            *(uint2*)&Tq[0][1][o] = make_uint2(tl[i][j][0], tl[i][j][1]);
          }
        }
      }

      // 4 phases, double-buffered panels, STAGE-AHEAD schedule:
      // phase t: [prefetch A-frags] barrier [B-frags from buf t] +
      //          [stage buf t+1 under MFMA shadow] + [MFMA].
      #pragma unroll 1
      for (int t = 0; t < 4; ++t) {
        const short* th = &Tq[t & 1][0][0];
        const short* tg = &Tq[t & 1][1][0];
        short* sh = &Tq[(t + 1) & 1][0][0];
        short* sg = &Tq[(t + 1) & 1][1][0];

        // A-fragments depend only on Y/Z (stable all phase-loop long):
        // issued above the barrier so their latency hides under the wait.
        const int k0 = (t << 5) + (quad << 3);
        bf16x8 ahY[2], alY[2], ahZ[2], alZ[2];
        #pragma unroll
        for (int i = 0; i < 2; ++i) {
          const int o = YIX(RB + lrow + 16*i, k0);
          ahY[i] = *(const bf16x8*)&Yhi[o];
          alY[i] = *(const bf16x8*)&Ylo[o];
        }
        if (doQ) {
          #pragma unroll
          for (int i = 0; i < 2; ++i) {
            const int o = YIX(RB + lrow + 16*i, k0);
            ahZ[i] = *(const bf16x8*)&Zhi[o];
            alZ[i] = *(const bf16x8*)&Zlo[o];
          }
        }

        __syncthreads();                   // publish Tq[t&1]

        const int kq = quad << 3;
        bf16x8 bh[4], bl[4];
        #pragma unroll
        for (int j = 0; j < 4; ++j) {
          const int o = tix(CB + 16*j + lrow, kq);
          bh[j] = *(const bf16x8*)&th[o];
          bl[j] = *(const bf16x8*)&tg[o];
        }

        // Stage NEXT phase's panel into the free buffer, hidden under the
        // MFMA cluster (buf[(t+1)&1] readers drained at this barrier).
        if (t < 3 && wr == t + 1) {
          #pragma unroll
          for (int i = 0; i < 2; ++i) {
            const int kp0 = (i << 4) + (quad << 2);
            #pragma unroll
            for (int j = 0; j < 4; ++j) {
              const int col = CB + 16*j + lrow;
              const int o = tix(col, kp0);
              *(uint2*)&sh[o] = make_uint2(tp[i][j][0], tp[i][j][1]);
              *(uint2*)&sg[o] = make_uint2(tl[i][j][0], tl[i][j][1]);
            }
          }
        }

        __builtin_amdgcn_s_setprio(1);
        #pragma unroll
        for (int i = 0; i < 2; ++i)
          #pragma unroll
          for (int j = 0; j < 4; ++j) { MFMA3(accP[i][j], ahY[i], alY[i], bh[j], bl[j]); }
        if (doQ) {
          #pragma unroll
          for (int i = 0; i < 2; ++i)
            #pragma unroll
            for (int j = 0; j < 4; ++j) { MFMA3(accQ[i][j], ahZ[i], alZ[i], bh[j], bl[j]); }
        }
        __builtin_amdgcn_s_setprio(0);
      }
      __syncthreads();   // all reads of Y/Z/Tq complete

      if (it < 5) {
        // write-back (packed b64 "transposed" store = same matrix by symmetry)
        const float yscale = (it == 1) ? rn : 1.0f;
        #pragma unroll
        for (int i = 0; i < 2; ++i)
          #pragma unroll
          for (int j = 0; j < 4; ++j) {
            const int col  = CB + 16*j + lrow;
            const int row0 = RB + 16*i + (quad << 2);
            const int o = YIX(col, row0);
            unsigned h01, l01, h23, l23;
            split_pair(yscale * accP[i][j][0], yscale * accP[i][j][1], h01, l01);
            split_pair(yscale * accP[i][j][2], yscale * accP[i][j][3], h23, l23);
            *(uint2*)&Yhi[o] = make_uint2(h01, h23);
            *(uint2*)&Ylo[o] = make_uint2(l01, l23);
            if (it == 1) {
              // Z1 = T: reuse the packed split regs directly
              *(uint2*)&Zhi[o] = make_uint2(tp[i][j][0], tp[i][j][1]);
              *(uint2*)&Zlo[o] = make_uint2(tl[i][j][0], tl[i][j][1]);
            } else {
              split_pair(accQ[i][j][0], accQ[i][j][1], h01, l01);
              split_pair(accQ[i][j][2], accQ[i][j][3], h23, l23);
              *(uint2*)&Zhi[o] = make_uint2(h01, h23);
              *(uint2*)&Zlo[o] = make_uint2(l01, l23);
            }
          }
        __syncthreads();
      } else {
        // final: out = Y5 * sqrt(normA)  (fire-and-forget; overlaps next init)
        float* ob = out + (size_t)b * (NN * NN);
        #pragma unroll
        for (int i = 0; i < 2; ++i)
          #pragma unroll
          for (int j = 0; j < 4; ++j) {
            const int col  = CB + 16*j + lrow;
            const int row0 = RB + 16*i + (quad << 2);
            #pragma unroll
            for (int r = 0; r < 4; ++r)
              ob[(size_t)(row0 + r) * NN + col] = accP[i][j][r] * s_out;
          }
      }
    }
  }
}

extern "C" void kernel_launch(void* const* d_in, const int* in_sizes, int n_in,
                              void* d_out, int out_size, void* d_ws, size_t ws_size,
                              hipStream_t stream) {
  const float* A = (const float*)d_in[0];
  float* out = (float*)d_out;
  ns_sqrt_kernel<<<dim3(512), dim3(512), 0, stream>>>(A, out);
}